// Round 21
// baseline (24.116 us; speedup 1.0000x reference)
//
#include <hip/hip_runtime.h>

// Problem constants (fixed by setup_inputs)
#define K   19
#define C   256
#define HF  64
#define WF  128
#define HW  (HF * WF)
#define BB  4
#define HL  512
#define WL  1024

// bf16-split-x3 distance error bound ~1e-3 worst-case; pixels whose top-2
// gap < TAU get the proven exact-f64 cooperative resolve.
#define TAU 0.03f

#define CPAD 264    // halfwords per centroid row: 528 B = 33 x 16 B
#define DPAD 66     // dwords per acc row
#define CHI_BYTES (K * CPAD * 2)          // 10032 B (16B-aligned: 10032=627*16)
#define POOL_BYTES (2 * CHI_BYTES)        // chi + clo = 20064 B; dbuf (16896 B) overlays

typedef __attribute__((ext_vector_type(8)))  short bf16x8;
typedef __attribute__((ext_vector_type(16))) float f32x16;

// R19 + occupancy doubling. R20 showed: longer per-wave stream at HALF the
// waves regresses (2/SIMD); R17-vs-R15 showed 8-vs-4 waves/SIMD helps. So:
// 4-way K-split (wave = K-quarter of one 32-px tile) -> 8192 waves total,
// and LDS shrunk to ~21.5 KB by OVERLAYING dbuf onto the chi/clo pool
// (dead after the MFMA loop; extra __syncthreads makes reuse safe) ->
// ~6-7 blocks/CU resident = ~6 waves/SIMD, 1.5x R19's coverage.
// Indexing = R19's with kh quarters (kh offset in BOTH A and B bases).
__global__ __launch_bounds__(256, 6) void centroid_mask_kernel(
    const float* __restrict__ feat0,   // feature_s2t
    const float* __restrict__ feat1,   // feature_target
    const float* __restrict__ cent0,   // centroids for map 0 (centroid_target)
    const float* __restrict__ cent1,   // centroids for map 1 (centroid_s2t)
    int* __restrict__ out)             // [2][BB][HL][WL] int32
{
    __shared__ __align__(16) unsigned char pool[POOL_BYTES];  // chi|clo, then dbuf
    __shared__ double c2p[K][8];             // exact ||c||^2 partials
    __shared__ double sc2d[K];               // exact ||c||^2 (f64)
    __shared__ float  sc2f[K];               // rounded-exact ||c||^2 (f32)

    unsigned short* __restrict__ chi = (unsigned short*)pool;
    unsigned short* __restrict__ clo = (unsigned short*)(pool + CHI_BYTES);
    float*          __restrict__ dbf = (float*)pool;   // [kh][reg][DPAD] overlay

    const int map = blockIdx.y;
    const float* __restrict__ feat = (map == 0) ? feat0 : feat1;
    const float* __restrict__ cent = (map == 0) ? cent0 : cent1;

    const int tid  = threadIdx.x;
    const int lane = tid & 63;
    const int wv   = __builtin_amdgcn_readfirstlane(tid >> 6);   // kh = 0..3

    // ---- stage split centroids into LDS (coalesced) + exact ||c||^2 ----
    for (int i = tid; i < K * C; i += 256) {
        const int k = i >> 8, c = i & (C - 1);
        const unsigned u = __float_as_uint(cent[i]);
        const float r = __uint_as_float(u) - __uint_as_float(u & 0xffff0000u);
        chi[k * CPAD + c] = (unsigned short)(u >> 16);
        clo[k * CPAD + c] = (unsigned short)(__float_as_uint(r) >> 16);
    }
    if (tid < K * 8) {
        const int k = tid >> 3, sl = tid & 7;
        const float* cp = cent + k * C + sl * 32;
        double s = 0.0;
        #pragma unroll
        for (int j = 0; j < 32; ++j) { double v = (double)cp[j]; s = fma(v, v, s); }
        c2p[k][sl] = s;
    }
    __syncthreads();
    if (tid < K) {
        double s = 0.0;
        #pragma unroll
        for (int j = 0; j < 8; ++j) s += c2p[tid][j];
        sc2d[tid] = s;
        sc2f[tid] = (float)s;
    }

    // ---- main: all 4 waves on ONE 32-px tile; wave = K-quarter (64 ch) ----
    const int kh   = wv;                           // K-quarter: 0..3
    const int hl2  = (lane >> 5) & 1;              // k-subchunk select
    const int pp   = blockIdx.x * 32 + (lane & 31);
    const int hw   = pp & (HW - 1);
    const int b    = pp >> 13;

    const float* __restrict__ fp = feat + (size_t)b * C * HW + hw;
    const int cb0  = kh * 64 + hl2 * 8;            // A channel base
    const int bidx = min(lane & 31, 18) * CPAD + kh * 64 + hl2 * 8;  // B base (kh!)

    f32x16 acc;
    #pragma unroll
    for (int r = 0; r < 16; ++r) acc[r] = 0.f;

    #pragma unroll
    for (int s = 0; s < 4; ++s) {                  // 4 K-steps of 16 channels
        const int cb = cb0 + s * 16;
        float fv[8];
        #pragma unroll
        for (int j = 0; j < 8; ++j)
            fv[j] = fp[(size_t)(cb + j) * HW];     // coalesced over lanes 0-31

        union { unsigned u[4]; bf16x8 v; } ah, al, bh, bl;
        #pragma unroll
        for (int j = 0; j < 4; ++j) {
            const unsigned u0 = __float_as_uint(fv[2*j]);
            const unsigned u1 = __float_as_uint(fv[2*j+1]);
            ah.u[j] = (u0 >> 16) | (u1 & 0xffff0000u);           // hi (truncate)
            const float r0 = fv[2*j]   - __uint_as_float(u0 & 0xffff0000u);
            const float r1 = fv[2*j+1] - __uint_as_float(u1 & 0xffff0000u);
            al.u[j] = (__float_as_uint(r0) >> 16)
                    | (__float_as_uint(r1) & 0xffff0000u);       // lo (truncate)
        }
        bh.v = *(const bf16x8*)&chi[bidx + s * 16];
        bl.v = *(const bf16x8*)&clo[bidx + s * 16];

        acc = __builtin_amdgcn_mfma_f32_32x32x16_bf16(ah.v, bh.v, acc, 0, 0, 0);
        acc = __builtin_amdgcn_mfma_f32_32x32x16_bf16(ah.v, bl.v, acc, 0, 0, 0);
        acc = __builtin_amdgcn_mfma_f32_32x32x16_bf16(al.v, bh.v, acc, 0, 0, 0);
    }

    __syncthreads();   // all waves done READING chi/clo -> pool reusable

    // dump acc into overlay: element (reg,lane) = D[px=(reg&3)+8(reg>>2)+4(lane>>5)][k=lane&31]
    {
        float* dst = &dbf[(kh * 16) * DPAD + hl2 * 32 + (lane & 31)];
        #pragma unroll
        for (int r = 0; r < 16; ++r) dst[r * DPAD] = acc[r];
    }
    __syncthreads();

    // ---- epilogue: wave 0; lanes 0-31 = pixels, all 64 lanes help resolve ----
    if (tid < 64) {
        const int px  = lane & 31;
        const int h   = (px >> 2) & 1;
        const int reg = (px & 3) | ((px >> 3) << 2);
        const int bse = h * 32;

        const int ppx = blockIdx.x * 32 + px;
        const int phw = ppx & (HW - 1);
        const int pb  = ppx >> 13;

        float d[K];
        #pragma unroll
        for (int k = 0; k < K; ++k) {
            const float s = (dbf[(0 * 16 + reg) * DPAD + bse + k]
                           + dbf[(1 * 16 + reg) * DPAD + bse + k])
                          + (dbf[(2 * 16 + reg) * DPAD + bse + k]
                           + dbf[(3 * 16 + reg) * DPAD + bse + k]);
            d[k] = sc2f[k] - 2.0f * s;
        }
        int best = 0; float m1 = d[0];
        #pragma unroll
        for (int k = 1; k < K; ++k) if (d[k] < m1) { m1 = d[k]; best = k; }

        unsigned cmask = 0u;
        #pragma unroll
        for (int k = 0; k < K; ++k) if (d[k] - m1 < TAU) cmask |= (1u << k);

        // cooperative exact-f64 resolve of flagged pixels (proven, R8)
        const bool need = (cmask & (cmask - 1)) != 0u;
        unsigned long long ball = __ballot(need && (lane < 32));
        while (ball) {
            const int sx = (int)__builtin_ctzll(ball);   // flagged px lane, 0..31
            ball &= ball - 1;
            const unsigned pm  = __shfl(cmask, sx, 64);
            const int      fhw = __shfl(phw,   sx, 64);
            const int      fb  = __shfl(pb,    sx, 64);
            const float* __restrict__ fcol = feat + (size_t)fb * C * HW + fhw;

            const int c0 = lane << 2;                    // channels 4l..4l+3
            double pf[4];
            #pragma unroll
            for (int j = 0; j < 4; ++j)
                pf[j] = (double)fcol[(size_t)(c0 + j) * HW];

            double bd = 1e300; int bi = 0;
            unsigned mm = pm;
            while (mm) {                      // ascending k, strict < tie-break
                const int k = (int)__builtin_ctz(mm);
                mm &= mm - 1;
                const float* __restrict__ ck = cent + (size_t)k * C + c0;
                double s = 0.0;
                #pragma unroll
                for (int j = 0; j < 4; ++j)
                    s = fma(pf[j], (double)ck[j], s);
                #pragma unroll
                for (int off = 1; off < 64; off <<= 1)
                    s += __shfl_xor(s, off, 64);
                const double dk = sc2d[k] - 2.0 * s;
                if (dk < bd) { bd = dk; bi = k; }
            }
            if (lane == sx) best = bi;        // all lanes agree on bi
        }

        // write the 8x8 nearest-upsampled block (lanes 0-31)
        if (lane < 32) {
            const int w  = phw & (WF - 1);
            const int hh = phw >> 7;
            int4 v = make_int4(best, best, best, best);
            int* __restrict__ ob = out + (size_t)map * (BB * HL * WL)
                                       + (size_t)pb * (HL * WL)
                                       + (size_t)(hh * 8) * WL + (size_t)(w * 8);
            #pragma unroll
            for (int r = 0; r < 8; ++r) {
                *(int4*)(ob + (size_t)r * WL)     = v;
                *(int4*)(ob + (size_t)r * WL + 4) = v;
            }
        }
    }
}

extern "C" void kernel_launch(void* const* d_in, const int* in_sizes, int n_in,
                              void* d_out, int out_size, void* d_ws, size_t ws_size,
                              hipStream_t stream) {
    const float* feature_s2t     = (const float*)d_in[0];
    const float* feature_target  = (const float*)d_in[1];
    // d_in[2], d_in[3]: labels — only shapes matter, unused
    const float* centroid_s2t    = (const float*)d_in[4];
    const float* centroid_target = (const float*)d_in[5];
    int* out = (int*)d_out;

    // 32 px per block, 4 waves = 4 K-quarters -> grid (1024, 2) = 2048 blocks
    dim3 grid(32768 / 32, 2);
    dim3 block(256);
    hipLaunchKernelGGL(centroid_mask_kernel, grid, block, 0, stream,
                       feature_s2t, feature_target,
                       centroid_target, centroid_s2t, out);
}